// Round 1
// baseline (306.087 us; speedup 1.0000x reference)
//
#include <hip/hip_runtime.h>

// ---------------------------------------------------------------------------
// EmbeddingGATHead: pool -> GATv2 (2 layers, 4 heads, block-diagonal mask) ->
// residual -> part-mean -> BN.  All fp32 for round 1 (correctness anchor).
//
// Node order (torch.chunk dim=1 -> cat dim=0): n = p*B + b  (p in [0,6), b in [0,32))
// Mask instance grouping: inst = n // 6, valid[n] = (n % 6) < img_num_ps[n // 6]
// ---------------------------------------------------------------------------

#define NNODES 192
#define CFEAT  2048

// ---- 1. Global average pool: features [32][12288][16][8] -> pool [192][2048]
// One wave per (n,c) row of 128 contiguous floats.
__global__ __launch_bounds__(256) void pool_kernel(const float* __restrict__ F,
                                                   float* __restrict__ POOL) {
    int wave = threadIdx.x >> 6, lane = threadIdx.x & 63;
    int r = blockIdx.x * 4 + wave;            // r in [0, 192*2048)
    int n = r >> 11, c = r & 2047;
    int p = n >> 5, b = n & 31;               // n = p*32 + b
    const float* src = F + (((size_t)b * 12288 + (size_t)p * 2048 + c) << 7);
    float2 v = *(const float2*)(src + (lane << 1));
    float acc = v.x + v.y;
    #pragma unroll
    for (int off = 32; off; off >>= 1) acc += __shfl_down(acc, off);
    if (lane == 0) POOL[r] = acc * (1.0f / 128.0f);
}

// ---- 2. Fused linear: Y{L,R}[n][h][d] = sum_c X[n][c] * W{l,r}[h][c][d] + b[h][d]
// fp32 tiled matmul: 64x64 block tile, 4x4 micro-tile, BK=16.
// grid = (3 mblk, 8 nblk, 8 z)  z<4: Wl head z -> YL ; z>=4: Wr head z-4 -> YR
__global__ __launch_bounds__(256) void linear_kernel(
    const float* __restrict__ X,
    const float* __restrict__ WL, const float* __restrict__ BL,
    const float* __restrict__ WR, const float* __restrict__ BR,
    float* __restrict__ YL, float* __restrict__ YR) {
    int mblk = blockIdx.x, nblk = blockIdx.y, z = blockIdx.z;
    int h = z & 3;
    const float* W  = (z < 4) ? WL : WR;
    const float* Bv = (z < 4) ? BL : BR;
    float*       Y  = (z < 4) ? YL : YR;

    __shared__ float as[16][64];   // [k][m]  (x tile, transposed)
    __shared__ float wsm[16][64];  // [k][n]

    int tid = threadIdx.x;
    int tm = tid >> 4, tn = tid & 15;

    const float* Wh = W + (size_t)h * (2048 * 512) + nblk * 64;
    const float* Xb = X + (size_t)mblk * 64 * 2048;

    float acc[4][4] = {};

    int la_m = tid >> 2;           // 0..63
    int la_k = (tid & 3) << 2;     // 0,4,8,12
    int lw_k = tid >> 4;           // 0..15
    int lw_c = (tid & 15) << 2;    // 0..60

    for (int k0 = 0; k0 < 2048; k0 += 16) {
        float4 a4 = *(const float4*)(Xb + (size_t)la_m * 2048 + k0 + la_k);
        float4 b4 = *(const float4*)(Wh + (size_t)(k0 + lw_k) * 512 + lw_c);
        __syncthreads();           // protect previous iteration's LDS reads
        as[la_k + 0][la_m] = a4.x;
        as[la_k + 1][la_m] = a4.y;
        as[la_k + 2][la_m] = a4.z;
        as[la_k + 3][la_m] = a4.w;
        *(float4*)&wsm[lw_k][lw_c] = b4;
        __syncthreads();
        #pragma unroll
        for (int k = 0; k < 16; ++k) {
            float4 av = *(const float4*)&as[k][tm << 2];
            float4 bv = *(const float4*)&wsm[k][tn << 2];
            float am[4] = {av.x, av.y, av.z, av.w};
            float bn[4] = {bv.x, bv.y, bv.z, bv.w};
            #pragma unroll
            for (int i = 0; i < 4; ++i)
                #pragma unroll
                for (int j = 0; j < 4; ++j)
                    acc[i][j] = fmaf(am[i], bn[j], acc[i][j]);
        }
    }

    int colb = nblk * 64 + (tn << 2);
    #pragma unroll
    for (int i = 0; i < 4; ++i) {
        int nrow = mblk * 64 + (tm << 2) + i;
        float4 bias = *(const float4*)(Bv + h * 512 + colb);
        float4 o;
        o.x = acc[i][0] + bias.x;
        o.y = acc[i][1] + bias.y;
        o.z = acc[i][2] + bias.z;
        o.w = acc[i][3] + bias.w;
        *(float4*)(Y + (size_t)nrow * 2048 + h * 512 + colb) = o;
    }
}

// ---- 3. Attention per (instance g, head h). Nodes 6g..6g+5; valid iff local q < NPS[g].
// Neighbor set of i: valid i -> all valid j in block; invalid i -> {i} (self loop only).
template <int LAYER>
__global__ __launch_bounds__(256) void attn_kernel(
    const float* XL, const float* XR,          // [192][4][512]  (no restrict: OUT may alias XR)
    const float* __restrict__ ATT,             // [4][512] (layer slice)
    const float* __restrict__ GBIAS,           // [2048]   (layer slice)
    const int* __restrict__ NPS,               // [32]
    const float* __restrict__ POOL,            // [192][2048] (layer 1 only)
    float* OUT) {                              // [192][2048]
    __shared__ float xls[6][512];
    __shared__ float xrs[6][512];
    __shared__ float atts[512];
    __shared__ float s_sm[6][6];
    __shared__ float alpha[6][6];

    int g = blockIdx.x, h = blockIdx.y;
    int tid = threadIdx.x;
    int cnt = NPS[g];

    for (int idx = tid; idx < 6 * 512; idx += 256) {
        int q = idx >> 9, d = idx & 511;
        size_t off = (size_t)(g * 6 + q) * 2048 + h * 512 + d;
        xls[q][d] = XL[off];
        xrs[q][d] = XR[off];
    }
    for (int d = tid; d < 512; d += 256) atts[d] = ATT[h * 512 + d];
    __syncthreads();

    // s[i][j] = sum_d att[d] * leaky_relu(xr[i][d] + xl[j][d], 0.2); 36 pairs over 4 waves
    int wv = tid >> 6, lane = tid & 63;
    for (int p = wv; p < 36; p += 4) {
        int i = p / 6, j = p % 6;
        float acc = 0.f;
        #pragma unroll
        for (int t = 0; t < 8; ++t) {
            int d = lane + t * 64;
            float v = xrs[i][d] + xls[j][d];
            v = (v >= 0.f) ? v : 0.2f * v;
            acc = fmaf(atts[d], v, acc);
        }
        #pragma unroll
        for (int off = 32; off; off >>= 1) acc += __shfl_down(acc, off);
        if (lane == 0) s_sm[i][j] = acc;
    }
    __syncthreads();

    // softmax per row i over its neighbor set
    if (tid < 6) {
        int i = tid;
        bool iv = i < cnt;
        float mx;
        if (iv) {
            mx = -1e30f;
            for (int j = 0; j < cnt; ++j) mx = fmaxf(mx, s_sm[i][j]);
        } else {
            mx = s_sm[i][i];
        }
        float e[6], sum = 0.f;
        for (int j = 0; j < 6; ++j) {
            bool nb = iv ? (j < cnt) : (j == i);
            e[j] = nb ? expf(s_sm[i][j] - mx) : 0.f;
            sum += e[j];
        }
        float inv = 1.f / sum;
        for (int j = 0; j < 6; ++j) alpha[i][j] = e[j] * inv;
    }
    __syncthreads();

    // out[i][d] = sum_j alpha[i][j] * xl[j][d]; epilogue per layer
    for (int idx = tid; idx < 6 * 512; idx += 256) {
        int q = idx >> 9, d = idx & 511;
        float acc = 0.f;
        #pragma unroll
        for (int j = 0; j < 6; ++j) acc = fmaf(alpha[q][j], xls[j][d], acc);
        int col = h * 512 + d;
        size_t off = (size_t)(g * 6 + q) * 2048 + col;
        float v = acc + GBIAS[col];
        if (LAYER == 0) {
            OUT[off] = (v > 0.f) ? v : expm1f(v);   // ELU
        } else {
            OUT[off] = v + POOL[off];               // graph_feat = x + pool
        }
    }
}

// ---- 4. Part-mean + BN: out[b][c] = gamma[c]*(mean_p gf[p*32+b][c] - mu[c]) / sqrt(var+eps)
__global__ __launch_bounds__(256) void final_kernel(
    const float* __restrict__ GF, const float* __restrict__ GAMMA,
    const float* __restrict__ MEAN, const float* __restrict__ VAR,
    float* __restrict__ OUTP) {
    int idx = blockIdx.x * 256 + threadIdx.x;   // [0, 65536)
    int c = idx & 2047, b = idx >> 11;
    float acc = 0.f;
    #pragma unroll
    for (int p = 0; p < 6; ++p) acc += GF[(size_t)(p * 32 + b) * 2048 + c];
    acc *= (1.f / 6.f);
    OUTP[idx] = GAMMA[c] * (acc - MEAN[c]) * rsqrtf(VAR[c] + 1e-5f);
}

extern "C" void kernel_launch(void* const* d_in, const int* in_sizes, int n_in,
                              void* d_out, int out_size, void* d_ws, size_t ws_size,
                              hipStream_t stream) {
    const float* F     = (const float*)d_in[0];
    const int*   nps   = (const int*)d_in[1];
    const float* Wl    = (const float*)d_in[2];
    const float* bl    = (const float*)d_in[3];
    const float* Wr    = (const float*)d_in[4];
    const float* br    = (const float*)d_in[5];
    const float* att   = (const float*)d_in[6];
    const float* gb    = (const float*)d_in[7];
    const float* gamma = (const float*)d_in[8];
    const float* mean  = (const float*)d_in[9];
    const float* var   = (const float*)d_in[10];
    float* out = (float*)d_out;
    float* ws  = (float*)d_ws;

    const size_t SZ = (size_t)NNODES * CFEAT;   // 393216 floats
    float* pool = ws;                            // [192][2048]
    float* x1   = ws + SZ;                       // layer-0 output activations
    float* xl   = ws + 2 * SZ;
    float* xr   = ws + 3 * SZ;

    // 1. pool
    pool_kernel<<<dim3((NNODES * CFEAT) / 4), dim3(256), 0, stream>>>(F, pool);

    const size_t WOFF = 4ull * 2048 * 512;       // per-layer weight stride

    // 2. layer 0: linears + attention (+bias, ELU)
    linear_kernel<<<dim3(3, 8, 8), dim3(256), 0, stream>>>(pool, Wl, bl, Wr, br, xl, xr);
    attn_kernel<0><<<dim3(32, 4), dim3(256), 0, stream>>>(xl, xr, att, gb, nps, nullptr, x1);

    // 3. layer 1: linears + attention (+bias, +pool residual) -> gf (in-place over xr;
    //    each block reads exactly the region it writes, reads complete before writes)
    linear_kernel<<<dim3(3, 8, 8), dim3(256), 0, stream>>>(x1, Wl + WOFF, bl + 2048,
                                                           Wr + WOFF, br + 2048, xl, xr);
    attn_kernel<1><<<dim3(32, 4), dim3(256), 0, stream>>>(xl, xr, att + 2048, gb + 2048,
                                                          nps, pool, xr);

    // 4. part-mean + BN
    final_kernel<<<dim3(256), dim3(256), 0, stream>>>(xr, gamma, mean, var, out);
}

// Round 2
// 159.436 us; speedup vs baseline: 1.9198x; 1.9198x over previous
//
#include <hip/hip_runtime.h>
#include <hip/hip_bf16.h>

// ---------------------------------------------------------------------------
// EmbeddingGATHead: pool -> GATv2 (2 layers, 4 heads, block-diag mask) ->
// residual -> part-mean -> BN.
// Round 2: linears via bf16 MFMA (fp32 accum), split-K=8 for occupancy.
// Node order: n = p*32 + b.  Instance g = n // 6, valid iff (n % 6) < nps[g].
// ---------------------------------------------------------------------------

#define NNODES 192
#define CFEAT  2048

typedef __attribute__((ext_vector_type(8))) short bf16x8;   // 8 bf16 = 4 VGPR
typedef __attribute__((ext_vector_type(4))) float f32x4;

__device__ inline unsigned short f2bf(float f) {           // RNE f32 -> bf16
    union { float f; unsigned u; } v; v.f = f;
    unsigned u = v.u;
    u += 0x7FFFu + ((u >> 16) & 1u);
    return (unsigned short)(u >> 16);
}

// ---- 1. Global average pool: features [32][12288][16][8] -> pool [192][2048]
// One wave per (n,c) row of 128 contiguous floats. Emits fp32 + bf16 copies.
__global__ __launch_bounds__(256) void pool_kernel(const float* __restrict__ F,
                                                   float* __restrict__ POOL,
                                                   unsigned short* __restrict__ POOLB) {
    int wave = threadIdx.x >> 6, lane = threadIdx.x & 63;
    int r = blockIdx.x * 4 + wave;            // r in [0, 192*2048)
    int n = r >> 11, c = r & 2047;
    int p = n >> 5, b = n & 31;               // n = p*32 + b
    const float* src = F + (((size_t)b * 12288 + (size_t)p * 2048 + c) << 7);
    float2 v = *(const float2*)(src + (lane << 1));
    float acc = v.x + v.y;
    #pragma unroll
    for (int off = 32; off; off >>= 1) acc += __shfl_down(acc, off);
    if (lane == 0) {
        float m = acc * (1.0f / 128.0f);
        POOL[r] = m;
        POOLB[r] = f2bf(m);
    }
}

// ---- 2. bf16 MFMA GEMM, split-K.
// P[sk][192][4096] += X[192][kbeg:kbeg+256] * W[k][4096-cols]
// col j: j<2048 -> Wl head j/512 dim j%512 ; j>=2048 -> Wr.
// grid (64 col-tiles of 64, 8 split-K). block 256 (4 waves, each 48 rows x 64 cols).
__global__ __launch_bounds__(256) void gemm_kernel(
    const unsigned short* __restrict__ X,    // bf16 [192][2048]
    const float* __restrict__ WL,            // fp32 [4][2048][512] (layer slice)
    const float* __restrict__ WR,
    float* __restrict__ P) {
    __shared__ unsigned short lA[192 * 40];  // [row][k], stride 40 bf16 (pad)
    __shared__ unsigned short lB[64 * 40];   // [col][k], stride 40

    int ct = blockIdx.x, sk = blockIdx.y;
    const float* Wb = ((ct & 32) ? WR : WL)
                    + (size_t)((ct >> 3) & 3) * (2048 * 512) + ((ct & 7) << 6);
    int kbeg = sk << 8;                       // 256-wide K chunk
    int t = threadIdx.x;
    int w = t >> 6, l = t & 63;

    f32x4 acc[3][4];
    #pragma unroll
    for (int i = 0; i < 3; ++i)
        #pragma unroll
        for (int j = 0; j < 4; ++j) acc[i][j] = {0.f, 0.f, 0.f, 0.f};

    for (int step = 0; step < 8; ++step) {
        int k0 = kbeg + (step << 5);
        // A: 192 rows x 32 bf16 = 768 x 16B chunks; 3 per thread
        uint4 av[3];
        #pragma unroll
        for (int i = 0; i < 3; ++i) {
            int chunk = t + (i << 8);
            int r = chunk >> 2, q = chunk & 3;
            av[i] = *(const uint4*)(X + (size_t)r * 2048 + k0 + (q << 3));
        }
        // B: wave w loads k-rows w*8..w*8+7, lane l = col; coalesced 256B rows
        float bv[8];
        #pragma unroll
        for (int i = 0; i < 8; ++i)
            bv[i] = Wb[(size_t)(k0 + (w << 3) + i) * 512 + l];

        __syncthreads();                      // previous step's LDS reads done
        #pragma unroll
        for (int i = 0; i < 3; ++i) {
            int chunk = t + (i << 8);
            int r = chunk >> 2, q = chunk & 3;
            *(uint4*)(lA + r * 40 + (q << 3)) = av[i];
        }
        unsigned short bs[8];
        #pragma unroll
        for (int i = 0; i < 8; ++i) bs[i] = f2bf(bv[i]);
        *(uint4*)(lB + l * 40 + (w << 3)) = *(uint4*)bs;
        __syncthreads();

        bf16x8 af[3], bfr[4];
        #pragma unroll
        for (int fi = 0; fi < 3; ++fi)
            af[fi] = *(const bf16x8*)(lA + (48 * w + 16 * fi + (l & 15)) * 40 + ((l >> 4) << 3));
        #pragma unroll
        for (int fj = 0; fj < 4; ++fj)
            bfr[fj] = *(const bf16x8*)(lB + (16 * fj + (l & 15)) * 40 + ((l >> 4) << 3));
        #pragma unroll
        for (int fi = 0; fi < 3; ++fi)
            #pragma unroll
            for (int fj = 0; fj < 4; ++fj)
                acc[fi][fj] = __builtin_amdgcn_mfma_f32_16x16x32_bf16(
                    af[fi], bfr[fj], acc[fi][fj], 0, 0, 0);
    }

    // epilogue: D row = (lane>>4)*4 + reg, col = lane&15  [m89-verified]
    float* Pb = P + (size_t)sk * (192 * 4096) + ((size_t)ct << 6);
    #pragma unroll
    for (int fi = 0; fi < 3; ++fi) {
        int rbase = 48 * w + 16 * fi + ((l >> 4) << 2);
        #pragma unroll
        for (int j = 0; j < 4; ++j) {
            float* dst = Pb + (size_t)(rbase + j) * 4096 + (l & 15);
            #pragma unroll
            for (int fj = 0; fj < 4; ++fj) dst[16 * fj] = acc[fi][fj][j];
        }
    }
}

// ---- 3. split-K reduce + bias: Y[n][j] = sum_sk P[sk][n][j] + bias[j]
__global__ __launch_bounds__(256) void reduce_kernel(
    const float* __restrict__ P, const float* __restrict__ BL,
    const float* __restrict__ BR, float* __restrict__ Y) {
    int idx = blockIdx.x * 256 + threadIdx.x;   // float4 index, 196608 total
    float4 s = *((const float4*)P + idx);
    #pragma unroll
    for (int sk = 1; sk < 8; ++sk) {
        float4 v = *((const float4*)(P + (size_t)sk * (192 * 4096)) + idx);
        s.x += v.x; s.y += v.y; s.z += v.z; s.w += v.w;
    }
    int col = (idx << 2) & 4095;
    const float* bias = (col < 2048) ? (BL + col) : (BR + (col - 2048));
    float4 b = *(const float4*)bias;
    s.x += b.x; s.y += b.y; s.z += b.z; s.w += b.w;
    *((float4*)Y + idx) = s;
}

// ---- 4. Attention per (instance g, head h). Y layout: [192][4096], xl=cols 0..2047,
// xr=cols 2048..4095 (col within side = h*512+d).
template <int LAYER>
__global__ __launch_bounds__(256) void attn_kernel(
    const float* __restrict__ Y,
    const float* __restrict__ ATT,             // [4][512] (layer slice)
    const float* __restrict__ GBIAS,           // [2048]   (layer slice)
    const int* __restrict__ NPS,               // [32]
    const float* __restrict__ POOL,            // [192][2048] (layer 1 only)
    float* __restrict__ OUTF,                  // layer 1: graph_feat fp32
    unsigned short* __restrict__ OUTB) {       // layer 0: x1 bf16
    __shared__ float xls[6][512];
    __shared__ float xrs[6][512];
    __shared__ float atts[512];
    __shared__ float s_sm[6][6];
    __shared__ float alpha[6][6];

    int g = blockIdx.x, h = blockIdx.y;
    int tid = threadIdx.x;
    int cnt = NPS[g];

    for (int idx = tid; idx < 6 * 512; idx += 256) {
        int q = idx >> 9, d = idx & 511;
        size_t off = (size_t)(g * 6 + q) * 4096 + h * 512 + d;
        xls[q][d] = Y[off];
        xrs[q][d] = Y[off + 2048];
    }
    for (int d = tid; d < 512; d += 256) atts[d] = ATT[h * 512 + d];
    __syncthreads();

    int wv = tid >> 6, lane = tid & 63;
    for (int p = wv; p < 36; p += 4) {
        int i = p / 6, j = p % 6;
        float acc = 0.f;
        #pragma unroll
        for (int u = 0; u < 8; ++u) {
            int d = lane + u * 64;
            float v = xrs[i][d] + xls[j][d];
            v = (v >= 0.f) ? v : 0.2f * v;
            acc = fmaf(atts[d], v, acc);
        }
        #pragma unroll
        for (int off = 32; off; off >>= 1) acc += __shfl_down(acc, off);
        if (lane == 0) s_sm[i][j] = acc;
    }
    __syncthreads();

    if (tid < 6) {
        int i = tid;
        bool iv = i < cnt;
        float mx;
        if (iv) {
            mx = -1e30f;
            for (int j = 0; j < cnt; ++j) mx = fmaxf(mx, s_sm[i][j]);
        } else {
            mx = s_sm[i][i];
        }
        float e[6], sum = 0.f;
        for (int j = 0; j < 6; ++j) {
            bool nb = iv ? (j < cnt) : (j == i);
            e[j] = nb ? expf(s_sm[i][j] - mx) : 0.f;
            sum += e[j];
        }
        float inv = 1.f / sum;
        for (int j = 0; j < 6; ++j) alpha[i][j] = e[j] * inv;
    }
    __syncthreads();

    for (int idx = tid; idx < 6 * 512; idx += 256) {
        int q = idx >> 9, d = idx & 511;
        float acc = 0.f;
        #pragma unroll
        for (int j = 0; j < 6; ++j) acc = fmaf(alpha[q][j], xls[j][d], acc);
        int col = h * 512 + d;
        size_t off = (size_t)(g * 6 + q) * 2048 + col;
        float v = acc + GBIAS[col];
        if (LAYER == 0) {
            v = (v > 0.f) ? v : expm1f(v);      // ELU
            OUTB[off] = f2bf(v);
        } else {
            OUTF[off] = v + POOL[off];          // graph_feat = x + pool
        }
    }
}

// ---- 5. Part-mean + BN
__global__ __launch_bounds__(256) void final_kernel(
    const float* __restrict__ GF, const float* __restrict__ GAMMA,
    const float* __restrict__ MEAN, const float* __restrict__ VAR,
    float* __restrict__ OUTP) {
    int idx = blockIdx.x * 256 + threadIdx.x;   // [0, 65536)
    int c = idx & 2047, b = idx >> 11;
    float acc = 0.f;
    #pragma unroll
    for (int p = 0; p < 6; ++p) acc += GF[(size_t)(p * 32 + b) * 2048 + c];
    acc *= (1.f / 6.f);
    OUTP[idx] = GAMMA[c] * (acc - MEAN[c]) * rsqrtf(VAR[c] + 1e-5f);
}

extern "C" void kernel_launch(void* const* d_in, const int* in_sizes, int n_in,
                              void* d_out, int out_size, void* d_ws, size_t ws_size,
                              hipStream_t stream) {
    const float* F     = (const float*)d_in[0];
    const int*   nps   = (const int*)d_in[1];
    const float* Wl    = (const float*)d_in[2];
    const float* bl    = (const float*)d_in[3];
    const float* Wr    = (const float*)d_in[4];
    const float* br    = (const float*)d_in[5];
    const float* att   = (const float*)d_in[6];
    const float* gb    = (const float*)d_in[7];
    const float* gamma = (const float*)d_in[8];
    const float* mean  = (const float*)d_in[9];
    const float* var   = (const float*)d_in[10];
    float* out = (float*)d_out;
    float* wsf = (float*)d_ws;

    const size_t SZ = (size_t)NNODES * CFEAT;   // 393216
    float* pool = wsf;                           // [192][2048] f32
    float* Y    = wsf + SZ;                      // [192][4096] f32
    float* gf   = Y + 2 * SZ;                    // [192][2048] f32
    float* P    = gf + SZ;                       // [8][192][4096] f32
    unsigned short* poolb = (unsigned short*)(P + 16 * SZ);  // [192][2048] bf16
    unsigned short* x1b   = poolb + SZ;                      // [192][2048] bf16

    const size_t WOFF = 4ull * 2048 * 512;       // per-layer weight stride

    // 1. pool (fp32 + bf16)
    pool_kernel<<<dim3((NNODES * CFEAT) / 4), dim3(256), 0, stream>>>(F, pool, poolb);

    // 2. layer 0
    gemm_kernel<<<dim3(64, 8), dim3(256), 0, stream>>>(poolb, Wl, Wr, P);
    reduce_kernel<<<dim3(768), dim3(256), 0, stream>>>(P, bl, br, Y);
    attn_kernel<0><<<dim3(32, 4), dim3(256), 0, stream>>>(Y, att, gb, nps, nullptr,
                                                          nullptr, x1b);

    // 3. layer 1
    gemm_kernel<<<dim3(64, 8), dim3(256), 0, stream>>>(x1b, Wl + WOFF, Wr + WOFF, P);
    reduce_kernel<<<dim3(768), dim3(256), 0, stream>>>(P, bl + 2048, br + 2048, Y);
    attn_kernel<1><<<dim3(32, 4), dim3(256), 0, stream>>>(Y, att + 2048, gb + 2048,
                                                          nps, pool, gf, nullptr);

    // 4. part-mean + BN
    final_kernel<<<dim3(256), dim3(256), 0, stream>>>(gf, gamma, mean, var, out);
}

// Round 3
// 122.958 us; speedup vs baseline: 2.4894x; 1.2967x over previous
//
#include <hip/hip_runtime.h>
#include <hip/hip_bf16.h>

// ---------------------------------------------------------------------------
// EmbeddingGATHead: pool -> GATv2 (2 layers, 4 heads, block-diag mask) ->
// residual -> part-mean -> BN.
// Round 3: gemm spill-free + prefetch + BN=32 (1024 blocks); reduce+bias fused
// into attn; pool float4. 6 dispatches total.
// Node order: n = p*32 + b.  Instance g = n // 6, valid iff (n % 6) < nps[g].
// ---------------------------------------------------------------------------

#define NNODES 192
#define CFEAT  2048

typedef __attribute__((ext_vector_type(8))) short bf16x8;   // 8 bf16 = 4 VGPR
typedef __attribute__((ext_vector_type(4))) float f32x4;

__device__ inline unsigned f2bf(float f) {                 // RNE f32 -> bf16
    union { float f; unsigned u; } v; v.f = f;
    unsigned u = v.u;
    u += 0x7FFFu + ((u >> 16) & 1u);
    return u >> 16;
}

// ---- 1. Global average pool: features [32][12288][16][8] -> pool [192][2048]
// One wave handles 2 consecutive (n,c) rows (256 contiguous floats) per iter.
__global__ __launch_bounds__(256) void pool_kernel(const float* __restrict__ F,
                                                   float* __restrict__ POOL,
                                                   unsigned short* __restrict__ POOLB) {
    int wave = threadIdx.x >> 6, lane = threadIdx.x & 63;
    #pragma unroll
    for (int it = 0; it < 12; ++it) {
        int dr = blockIdx.x * 4 + wave + it * 16384;   // [0, 196608)
        int r0 = dr * 2;                               // (n,c) pair index
        int n = r0 >> 11, c0 = r0 & 2047;
        int p = n >> 5, b = n & 31;                    // n = p*32 + b
        const float* src = F + (((size_t)b * 12288 + (size_t)p * 2048 + c0) << 7);
        float4 v = *(const float4*)(src + (lane << 2));
        float acc = (v.x + v.y) + (v.z + v.w);
        acc += __shfl_down(acc, 16);
        acc += __shfl_down(acc, 8);
        acc += __shfl_down(acc, 4);
        acc += __shfl_down(acc, 2);
        acc += __shfl_down(acc, 1);
        if ((lane & 31) == 0) {                        // lanes 0 and 32
            int r = r0 + (lane >> 5);
            float m = acc * (1.0f / 128.0f);
            POOL[r] = m;
            POOLB[r] = (unsigned short)f2bf(m);
        }
    }
}

// ---- 2. bf16 MFMA GEMM, split-K=8, BN=32.  grid (128 col-tiles, 8 sk).
// P[sk][192][4096] = X[192][sk*256:(sk+1)*256] * W-cols(ct*32..ct*32+31)
// 4 waves: wave w owns rows 48w..48w+47 (3 row-frags) x 32 cols (2 col-frags).
__global__ __launch_bounds__(256) void gemm_kernel(
    const unsigned short* __restrict__ X,    // bf16 [192][2048]
    const float* __restrict__ WL,            // fp32 [4][2048][512] (layer slice)
    const float* __restrict__ WR,
    float* __restrict__ P) {
    __shared__ unsigned short lA[192 * 40];  // [row][k], stride 40 bf16
    __shared__ unsigned short lB[32 * 40];   // [col][k], stride 40

    int ct = blockIdx.x, sk = blockIdx.y;
    const float* Wb = (ct >= 64 ? WR : WL)
                    + (size_t)((ct & 63) >> 4) * (2048 * 512) + ((ct & 15) << 5);
    int kbeg = sk << 8;
    int t = threadIdx.x, w = t >> 6, l = t & 63;
    int rA = t >> 2, qA = t & 3;                 // A: 3 x uint4 per thread
    int colB = t & 31, kgB = t >> 5;             // B: 4 k-rows per thread

    f32x4 acc[3][2];
    #pragma unroll
    for (int i = 0; i < 3; ++i)
        #pragma unroll
        for (int j = 0; j < 2; ++j) acc[i][j] = {0.f, 0.f, 0.f, 0.f};

    // prologue loads (named regs, no private arrays)
    uint4 av0, av1, av2;
    float bv0, bv1, bv2, bv3;
    {
        const unsigned short* xp = X + (size_t)rA * 2048 + kbeg + qA * 8;
        av0 = *(const uint4*)(xp);
        av1 = *(const uint4*)(xp + 64 * 2048);
        av2 = *(const uint4*)(xp + 128 * 2048);
        const float* wp = Wb + (size_t)(kbeg + kgB * 4) * 512 + colB;
        bv0 = wp[0]; bv1 = wp[512]; bv2 = wp[1024]; bv3 = wp[1536];
    }

    for (int step = 0; step < 8; ++step) {
        __syncthreads();                         // prev step's LDS reads done
        *(uint4*)(lA + rA * 40 + qA * 8) = av0;
        *(uint4*)(lA + (rA + 64) * 40 + qA * 8) = av1;
        *(uint4*)(lA + (rA + 128) * 40 + qA * 8) = av2;
        uint2 bw;
        bw.x = f2bf(bv0) | (f2bf(bv1) << 16);
        bw.y = f2bf(bv2) | (f2bf(bv3) << 16);
        *(uint2*)(lB + colB * 40 + kgB * 4) = bw;
        __syncthreads();

        if (step < 7) {                          // prefetch next step
            int k0 = kbeg + ((step + 1) << 5);
            const unsigned short* xp = X + (size_t)rA * 2048 + k0 + qA * 8;
            av0 = *(const uint4*)(xp);
            av1 = *(const uint4*)(xp + 64 * 2048);
            av2 = *(const uint4*)(xp + 128 * 2048);
            const float* wp = Wb + (size_t)(k0 + kgB * 4) * 512 + colB;
            bv0 = wp[0]; bv1 = wp[512]; bv2 = wp[1024]; bv3 = wp[1536];
        }

        int lr = l & 15, lk = (l >> 4) << 3;
        bf16x8 af0 = *(const bf16x8*)(lA + (48 * w + lr) * 40 + lk);
        bf16x8 af1 = *(const bf16x8*)(lA + (48 * w + 16 + lr) * 40 + lk);
        bf16x8 af2 = *(const bf16x8*)(lA + (48 * w + 32 + lr) * 40 + lk);
        bf16x8 bf0 = *(const bf16x8*)(lB + lr * 40 + lk);
        bf16x8 bf1 = *(const bf16x8*)(lB + (16 + lr) * 40 + lk);
        acc[0][0] = __builtin_amdgcn_mfma_f32_16x16x32_bf16(af0, bf0, acc[0][0], 0, 0, 0);
        acc[0][1] = __builtin_amdgcn_mfma_f32_16x16x32_bf16(af0, bf1, acc[0][1], 0, 0, 0);
        acc[1][0] = __builtin_amdgcn_mfma_f32_16x16x32_bf16(af1, bf0, acc[1][0], 0, 0, 0);
        acc[1][1] = __builtin_amdgcn_mfma_f32_16x16x32_bf16(af1, bf1, acc[1][1], 0, 0, 0);
        acc[2][0] = __builtin_amdgcn_mfma_f32_16x16x32_bf16(af2, bf0, acc[2][0], 0, 0, 0);
        acc[2][1] = __builtin_amdgcn_mfma_f32_16x16x32_bf16(af2, bf1, acc[2][1], 0, 0, 0);
    }

    // epilogue: D row = (lane>>4)*4 + reg, col = lane&15  [m89-verified]
    float* Pb = P + (size_t)sk * (192 * 4096) + (ct << 5);
    #pragma unroll
    for (int fi = 0; fi < 3; ++fi) {
        int rbase = 48 * w + 16 * fi + ((l >> 4) << 2);
        #pragma unroll
        for (int j = 0; j < 4; ++j) {
            float* dst = Pb + (size_t)(rbase + j) * 4096 + (l & 15);
            dst[0]  = acc[fi][0][j];
            dst[16] = acc[fi][1][j];
        }
    }
}

// ---- 3. Attention per (instance g, head h), with fused split-K reduce + bias.
template <int LAYER>
__global__ __launch_bounds__(256) void attn_kernel(
    const float* __restrict__ P,               // [8][192][4096]
    const float* __restrict__ BL,              // [4][512] bias lin_l (layer slice)
    const float* __restrict__ BR,              // [4][512] bias lin_r
    const float* __restrict__ ATT,             // [4][512] (layer slice)
    const float* __restrict__ GBIAS,           // [2048]   (layer slice)
    const int* __restrict__ NPS,               // [32]
    const float* __restrict__ POOL,            // [192][2048] (layer 1 only)
    float* __restrict__ OUTF,                  // layer 1: graph_feat fp32
    unsigned short* __restrict__ OUTB) {       // layer 0: x1 bf16
    __shared__ float xls[6][512];
    __shared__ float xrs[6][512];
    __shared__ float atts[512];
    __shared__ float s_sm[6][6];
    __shared__ float alpha[6][6];

    int g = blockIdx.x, h = blockIdx.y;
    int tid = threadIdx.x;
    int cnt = NPS[g];

    for (int idx = tid; idx < 6 * 512; idx += 256) {
        int q = idx >> 9, d = idx & 511;
        int col = h * 512 + d;
        size_t base = (size_t)(g * 6 + q) * 4096 + col;
        float sl = BL[col], sr = BR[col];
        #pragma unroll
        for (int sk = 0; sk < 8; ++sk) {
            const float* Ps = P + (size_t)sk * (192 * 4096) + base;
            sl += Ps[0];
            sr += Ps[2048];
        }
        xls[q][d] = sl;
        xrs[q][d] = sr;
    }
    for (int d = tid; d < 512; d += 256) atts[d] = ATT[h * 512 + d];
    __syncthreads();

    // s[i][j] = sum_d att[d] * leaky_relu(xr[i][d] + xl[j][d], 0.2)
    int wv = tid >> 6, lane = tid & 63;
    for (int p = wv; p < 36; p += 4) {
        int i = p / 6, j = p % 6;
        float acc = 0.f;
        #pragma unroll
        for (int u = 0; u < 8; ++u) {
            int d = lane + u * 64;
            float v = xrs[i][d] + xls[j][d];
            v = (v >= 0.f) ? v : 0.2f * v;
            acc = fmaf(atts[d], v, acc);
        }
        #pragma unroll
        for (int off = 32; off; off >>= 1) acc += __shfl_down(acc, off);
        if (lane == 0) s_sm[i][j] = acc;
    }
    __syncthreads();

    // softmax per row over neighbor set (valid i -> all valid j; invalid -> self)
    if (tid < 6) {
        int i = tid;
        bool iv = i < cnt;
        float mx;
        if (iv) {
            mx = -1e30f;
            for (int j = 0; j < cnt; ++j) mx = fmaxf(mx, s_sm[i][j]);
        } else {
            mx = s_sm[i][i];
        }
        float e[6], sum = 0.f;
        for (int j = 0; j < 6; ++j) {
            bool nb = iv ? (j < cnt) : (j == i);
            e[j] = nb ? expf(s_sm[i][j] - mx) : 0.f;
            sum += e[j];
        }
        float inv = 1.f / sum;
        for (int j = 0; j < 6; ++j) alpha[i][j] = e[j] * inv;
    }
    __syncthreads();

    for (int idx = tid; idx < 6 * 512; idx += 256) {
        int q = idx >> 9, d = idx & 511;
        float acc = 0.f;
        #pragma unroll
        for (int j = 0; j < 6; ++j) acc = fmaf(alpha[q][j], xls[j][d], acc);
        int col = h * 512 + d;
        size_t off = (size_t)(g * 6 + q) * 2048 + col;
        float v = acc + GBIAS[col];
        if (LAYER == 0) {
            v = (v > 0.f) ? v : expm1f(v);      // ELU
            OUTB[off] = (unsigned short)f2bf(v);
        } else {
            OUTF[off] = v + POOL[off];          // graph_feat = x + pool
        }
    }
}

// ---- 4. Part-mean + BN
__global__ __launch_bounds__(256) void final_kernel(
    const float* __restrict__ GF, const float* __restrict__ GAMMA,
    const float* __restrict__ MEAN, const float* __restrict__ VAR,
    float* __restrict__ OUTP) {
    int idx = blockIdx.x * 256 + threadIdx.x;   // [0, 65536)
    int c = idx & 2047, b = idx >> 11;
    float acc = 0.f;
    #pragma unroll
    for (int p = 0; p < 6; ++p) acc += GF[(size_t)(p * 32 + b) * 2048 + c];
    acc *= (1.f / 6.f);
    OUTP[idx] = GAMMA[c] * (acc - MEAN[c]) * rsqrtf(VAR[c] + 1e-5f);
}

extern "C" void kernel_launch(void* const* d_in, const int* in_sizes, int n_in,
                              void* d_out, int out_size, void* d_ws, size_t ws_size,
                              hipStream_t stream) {
    const float* F     = (const float*)d_in[0];
    const int*   nps   = (const int*)d_in[1];
    const float* Wl    = (const float*)d_in[2];
    const float* bl    = (const float*)d_in[3];
    const float* Wr    = (const float*)d_in[4];
    const float* br    = (const float*)d_in[5];
    const float* att   = (const float*)d_in[6];
    const float* gb    = (const float*)d_in[7];
    const float* gamma = (const float*)d_in[8];
    const float* mean  = (const float*)d_in[9];
    const float* var   = (const float*)d_in[10];
    float* out = (float*)d_out;
    float* wsf = (float*)d_ws;

    const size_t SZ = (size_t)NNODES * CFEAT;   // 393216
    float* pool = wsf;                           // [192][2048] f32
    float* gf   = wsf + SZ;                      // [192][2048] f32
    float* P    = wsf + 2 * SZ;                  // [8][192][4096] f32 (16*SZ)
    unsigned short* poolb = (unsigned short*)(wsf + 18 * SZ);  // [192][2048] bf16
    unsigned short* x1b   = poolb + SZ;                        // [192][2048] bf16

    const size_t WOFF = 4ull * 2048 * 512;       // per-layer weight stride

    // 1. pool (fp32 + bf16)
    pool_kernel<<<dim3(4096), dim3(256), 0, stream>>>(F, pool, poolb);

    // 2. layer 0
    gemm_kernel<<<dim3(128, 8), dim3(256), 0, stream>>>(poolb, Wl, Wr, P);
    attn_kernel<0><<<dim3(32, 4), dim3(256), 0, stream>>>(P, bl, br, att, gb, nps,
                                                          nullptr, nullptr, x1b);

    // 3. layer 1
    gemm_kernel<<<dim3(128, 8), dim3(256), 0, stream>>>(x1b, Wl + WOFF, Wr + WOFF, P);
    attn_kernel<1><<<dim3(32, 4), dim3(256), 0, stream>>>(P, bl + 2048, br + 2048,
                                                          att + 2048, gb + 2048,
                                                          nps, pool, gf, nullptr);

    // 4. part-mean + BN
    final_kernel<<<dim3(256), dim3(256), 0, stream>>>(gf, gamma, mean, var, out);
}